// Round 1
// baseline (191.043 us; speedup 1.0000x reference)
//
#include <hip/hip_runtime.h>
#include <hip/hip_fp16.h>

// Problem: score[e] = relu(h[src[e]]@W1s + h[dst[e]]@W1d + b1) @ W2 + b2
// N_NODES=100000, N_EDGES=1600000, H=64.
//
// Strategy: per-node precompute P = h@W1s + b1, Q = h@W1d (fp16, L3-resident),
// then per-edge gather + relu + dot(w2).

#define HF 64

// ---------------- Phase 1: per-node projection ----------------
// blockDim = 128: thread ct in [0,128) owns output column ct.
//   ct <  64 : P[node][ct]  = sum_k h[node][k]*W1[k][ct]      + b1[ct]
//   ct >= 64 : Q[node][ct-64] = sum_k h[node][k]*W1[64+k][ct-64]
// W column held in 64 VGPRs; h row read with wave-uniform float4 loads.
__global__ __launch_bounds__(128) void node_proj_kernel(
    const float* __restrict__ h, const float* __restrict__ W1,
    const float* __restrict__ b1, __half* __restrict__ P,
    __half* __restrict__ Q, int n_nodes)
{
    const int ct  = threadIdx.x;       // 0..127
    const int c   = ct & 63;
    const bool isQ = ct >= 64;

    // Load my W1 column into registers (coalesced across lanes for fixed k).
    float wc[64];
    const float* wbase = W1 + (isQ ? (64 * 64) : 0) + c;
    #pragma unroll
    for (int k = 0; k < 64; ++k) wc[k] = wbase[k * 64];

    const float bias = isQ ? 0.0f : b1[c];
    __half* outbase = (isQ ? Q : P) + c;

    for (int node = blockIdx.x; node < n_nodes; node += gridDim.x) {
        const float4* hv = (const float4*)(h + (size_t)node * HF);
        float a0 = 0.f, a1 = 0.f, a2 = 0.f, a3 = 0.f;
        #pragma unroll
        for (int k4 = 0; k4 < 16; ++k4) {
            float4 v = hv[k4];   // wave-uniform address -> scalar load
            a0 = fmaf(v.x, wc[k4 * 4 + 0], a0);
            a1 = fmaf(v.y, wc[k4 * 4 + 1], a1);
            a2 = fmaf(v.z, wc[k4 * 4 + 2], a2);
            a3 = fmaf(v.w, wc[k4 * 4 + 3], a3);
        }
        float r = (a0 + a1) + (a2 + a3) + bias;
        outbase[(size_t)node * HF] = __float2half(r);
    }
}

// ---------------- Phase 2: per-edge score ----------------
// 8 lanes per edge; lane `sub` owns features j0=sub*8 .. j0+7.
// Each lane: one 16B load from P[src] row + one 16B load from Q[dst] row,
// relu+dot with w2 in registers, butterfly reduce over the 8-lane group.
__global__ __launch_bounds__(256) void edge_score_kernel(
    const __half* __restrict__ P, const __half* __restrict__ Q,
    const int* __restrict__ src, const int* __restrict__ dst,
    const float* __restrict__ W2, const float* __restrict__ b2,
    float* __restrict__ out, int n_edges)
{
    const int tid      = blockIdx.x * blockDim.x + threadIdx.x;
    const int sub      = tid & 7;
    const int group    = tid >> 3;
    const int n_groups = (gridDim.x * blockDim.x) >> 3;
    const int j0       = sub * 8;

    float w2v[8];
    #pragma unroll
    for (int i = 0; i < 8; ++i) w2v[i] = W2[j0 + i];
    const float bias2 = b2[0];

    for (int e = group; e < n_edges; e += n_groups) {
        const int s = src[e];
        const int d = dst[e];
        const uint4 pv = *(const uint4*)(P + (size_t)s * HF + j0);
        const uint4 qv = *(const uint4*)(Q + (size_t)d * HF + j0);
        const __half2* ph = (const __half2*)&pv;
        const __half2* qh = (const __half2*)&qv;

        float acc = 0.f;
        #pragma unroll
        for (int i = 0; i < 4; ++i) {
            float2 pf = __half22float2(ph[i]);
            float2 qf = __half22float2(qh[i]);
            float x0 = fmaxf(pf.x + qf.x, 0.f);
            float x1 = fmaxf(pf.y + qf.y, 0.f);
            acc = fmaf(x0, w2v[i * 2 + 0], acc);
            acc = fmaf(x1, w2v[i * 2 + 1], acc);
        }
        // reduce over the 8-lane group
        acc += __shfl_xor(acc, 4, 8);
        acc += __shfl_xor(acc, 2, 8);
        acc += __shfl_xor(acc, 1, 8);
        if (sub == 0) out[e] = acc + bias2;
    }
}

extern "C" void kernel_launch(void* const* d_in, const int* in_sizes, int n_in,
                              void* d_out, int out_size, void* d_ws, size_t ws_size,
                              hipStream_t stream) {
    const float* h   = (const float*)d_in[0];
    const int*   src = (const int*)d_in[1];
    const int*   dst = (const int*)d_in[2];
    const float* W1  = (const float*)d_in[3];
    const float* b1  = (const float*)d_in[4];
    const float* W2  = (const float*)d_in[5];
    const float* b2  = (const float*)d_in[6];
    float* out = (float*)d_out;

    const int n_nodes = in_sizes[0] / HF;
    const int n_edges = in_sizes[1];

    __half* P = (__half*)d_ws;
    __half* Q = P + (size_t)n_nodes * HF;

    node_proj_kernel<<<2048, 128, 0, stream>>>(h, W1, b1, P, Q, n_nodes);
    edge_score_kernel<<<3072, 256, 0, stream>>>(P, Q, src, dst, W2, b2, out, n_edges);
}